// Round 1
// baseline (606.134 us; speedup 1.0000x reference)
//
#include <hip/hip_runtime.h>

// GCN 2-layer forward, f32.
// Key algebra: A_hat(X@W1) = (A_hat X)@W1  -> aggregate 64-wide X rows, not
// 128-wide XW1 rows; layer 2 reduces to scalar aggregation of s = h@W2.

#define NNODES 100000
#define INF 64
#define HID 128

__global__ void k_init_deg(float* deg, int n) {
    int i = blockIdx.x * blockDim.x + threadIdx.x;
    if (i < n) deg[i] = 1.0f;  // self loop
}

__global__ void k_deg(const int* __restrict__ dst, float* __restrict__ deg, int nE) {
    int e = blockIdx.x * blockDim.x + threadIdx.x;
    if (e < nE) {
        int d = dst[e];
        if ((unsigned)d < (unsigned)NNODES) atomicAdd(&deg[d], 1.0f);
    }
}

__global__ void k_rsqrt(float* deg, int n) {
    int i = blockIdx.x * blockDim.x + threadIdx.x;
    if (i < n) deg[i] = 1.0f / sqrtf(deg[i]);
}

// aggX[i][:] = dinv[i]^2 * X[i][:]   (self-loop term; initializes aggX)
__global__ void k_self_init(const float* __restrict__ X, const float* __restrict__ dinv,
                            float* __restrict__ agg, int n) {
    int i = blockIdx.x * blockDim.x + threadIdx.x;  // float4 index
    int total = n * (INF / 4);
    if (i < total) {
        int node = i >> 4;  // i / (64/4)
        float d = dinv[node];
        float c = d * d;
        float4 x = ((const float4*)X)[i];
        float4 r;
        r.x = c * x.x; r.y = c * x.y; r.z = c * x.z; r.w = c * x.w;
        ((float4*)agg)[i] = r;
    }
}

// one wave per edge (grid-stride): lane k adds norm*X[src][k] into aggX[dst][k]
__global__ __launch_bounds__(256) void k_scatter(const float* __restrict__ X,
                                                 const int* __restrict__ srcA,
                                                 const int* __restrict__ dstA,
                                                 const float* __restrict__ dinv,
                                                 float* __restrict__ agg, int nE) {
    int gt = blockIdx.x * blockDim.x + threadIdx.x;
    int wid = gt >> 6;
    int lane = gt & 63;
    int nw = (gridDim.x * blockDim.x) >> 6;
    for (int e = wid; e < nE; e += nw) {
        int s = srcA[e];
        int d = dstA[e];
        if ((unsigned)s < (unsigned)NNODES && (unsigned)d < (unsigned)NNODES) {
            float nrm = dinv[s] * dinv[d];
            atomicAdd(&agg[d * INF + lane], nrm * X[s * INF + lane]);
        }
    }
}

// fused: s[i] = dot( relu(aggX[i] @ W1 + b1), W2 )   -- wave per node
__global__ __launch_bounds__(256) void k_mlp(const float* __restrict__ agg,
                                             const float* __restrict__ W1,
                                             const float* __restrict__ b1,
                                             const float* __restrict__ W2,
                                             float* __restrict__ sOut, int n) {
    __shared__ float W1s[INF * HID];   // 32 KB
    __shared__ float b1s[HID];
    __shared__ float W2s[HID];
    for (int i = threadIdx.x; i < INF * HID / 4; i += blockDim.x)
        ((float4*)W1s)[i] = ((const float4*)W1)[i];
    if (threadIdx.x < HID) {
        b1s[threadIdx.x] = b1[threadIdx.x];
        W2s[threadIdx.x] = W2[threadIdx.x];
    }
    __syncthreads();

    int lane = threadIdx.x & 63;
    int wid = (blockIdx.x * blockDim.x + threadIdx.x) >> 6;
    int nw = (gridDim.x * blockDim.x) >> 6;
    for (int node = wid; node < n; node += nw) {
        float xv = agg[node * INF + lane];  // lane holds aggX[node][lane]
        float a0 = 0.0f, a1 = 0.0f;
#pragma unroll
        for (int k = 0; k < INF; ++k) {
            float xk = __shfl(xv, k, 64);
            a0 = fmaf(xk, W1s[k * HID + lane], a0);
            a1 = fmaf(xk, W1s[k * HID + 64 + lane], a1);
        }
        float h0 = fmaxf(a0 + b1s[lane], 0.0f);
        float h1 = fmaxf(a1 + b1s[64 + lane], 0.0f);
        float p = h0 * W2s[lane] + h1 * W2s[64 + lane];
#pragma unroll
        for (int off = 32; off > 0; off >>= 1) p += __shfl_xor(p, off, 64);
        if (lane == 0) sOut[node] = p;
    }
}

__global__ void k_out_init(const float* __restrict__ sv, const float* __restrict__ dinv,
                           const float* __restrict__ b2, float* __restrict__ out, int n) {
    int i = blockIdx.x * blockDim.x + threadIdx.x;
    if (i < n) out[i] = dinv[i] * dinv[i] * sv[i] + b2[0];
}

__global__ void k_out_edges(const int* __restrict__ srcA, const int* __restrict__ dstA,
                            const float* __restrict__ dinv, const float* __restrict__ sv,
                            float* __restrict__ out, int nE) {
    int e = blockIdx.x * blockDim.x + threadIdx.x;
    if (e < nE) {
        int s = srcA[e];
        int d = dstA[e];
        if ((unsigned)s < (unsigned)NNODES && (unsigned)d < (unsigned)NNODES)
            atomicAdd(&out[d], dinv[s] * dinv[d] * sv[s]);
    }
}

extern "C" void kernel_launch(void* const* d_in, const int* in_sizes, int n_in,
                              void* d_out, int out_size, void* d_ws, size_t ws_size,
                              hipStream_t stream) {
    const float* X  = (const float*)d_in[0];
    const int*   ei = (const int*)d_in[1];   // int32 (jax x64 disabled demotes int64)
    const float* W1 = (const float*)d_in[2];
    const float* b1 = (const float*)d_in[3];
    const float* W2 = (const float*)d_in[4];
    const float* b2 = (const float*)d_in[5];

    int N = in_sizes[0] / INF;     // 100000
    int E = in_sizes[1] / 2;       // 1600000
    const int* srcA = ei;
    const int* dstA = ei + E;

    float* wsf  = (float*)d_ws;
    float* dinv = wsf;                      // N floats (doubles as deg)
    float* agg  = wsf + N;                  // N*64 floats (400000 B offset, 16B-aligned)
    float* sv   = agg + (size_t)N * INF;    // N floats
    float* out  = (float*)d_out;

    int nb;
    nb = (N + 255) / 256;
    k_init_deg<<<nb, 256, 0, stream>>>(dinv, N);
    nb = (E + 255) / 256;
    k_deg<<<nb, 256, 0, stream>>>(dstA, dinv, E);
    nb = (N + 255) / 256;
    k_rsqrt<<<nb, 256, 0, stream>>>(dinv, N);
    nb = (N * (INF / 4) + 255) / 256;
    k_self_init<<<nb, 256, 0, stream>>>(X, dinv, agg, N);
    k_scatter<<<4096, 256, 0, stream>>>(X, srcA, dstA, dinv, agg, E);
    k_mlp<<<1024, 256, 0, stream>>>(agg, W1, b1, W2, sv, N);
    nb = (N + 255) / 256;
    k_out_init<<<nb, 256, 0, stream>>>(sv, dinv, b2, out, N);
    nb = (E + 255) / 256;
    k_out_edges<<<nb, 256, 0, stream>>>(srcA, dstA, dinv, sv, out, E);
}

// Round 2
// 510.447 us; speedup vs baseline: 1.1875x; 1.1875x over previous
//
#include <hip/hip_runtime.h>

// GCN 2-layer forward, f32 — CSR-gather formulation (no f32 device atomics).
// Algebra: A_hat(X@W1) = (A_hat X)@W1; layer 2 is scalar aggregation of s=h@W2.
// Pipeline: histogram -> block scan -> CSR fill -> fused gather+MLP -> scalar gather.

#define NNODES 100000
#define INF 64
#define HID 128

__global__ void k_zero(int* p, int n) {
    int i = blockIdx.x * blockDim.x + threadIdx.x;
    if (i < n) p[i] = 0;
}

__global__ void k_hist(const int* __restrict__ dst, int* __restrict__ cnt, int nE) {
    int e = blockIdx.x * blockDim.x + threadIdx.x;
    if (e < nE) {
        int d = dst[e];
        if ((unsigned)d < (unsigned)NNODES) atomicAdd(&cnt[d], 1);
    }
}

__global__ void k_dinv(const int* __restrict__ cnt, float* __restrict__ dinv, int n) {
    int i = blockIdx.x * blockDim.x + threadIdx.x;
    if (i < n) dinv[i] = rsqrtf((float)(cnt[i] + 1));  // +1 self loop
}

// block-level exclusive scan: 256 thr x 4 elems = 1024/block
__global__ void k_scan1(const int* __restrict__ cnt, int* __restrict__ excl,
                        int* __restrict__ bsums, int n) {
    __shared__ int tmp[256];
    int tid = threadIdx.x;
    int base = blockIdx.x * 1024 + tid * 4;
    int v0 = (base + 0 < n) ? cnt[base + 0] : 0;
    int v1 = (base + 1 < n) ? cnt[base + 1] : 0;
    int v2 = (base + 2 < n) ? cnt[base + 2] : 0;
    int v3 = (base + 3 < n) ? cnt[base + 3] : 0;
    int t = v0 + v1 + v2 + v3;
    tmp[tid] = t;
    __syncthreads();
    for (int off = 1; off < 256; off <<= 1) {
        int u = (tid >= off) ? tmp[tid - off] : 0;
        __syncthreads();
        tmp[tid] += u;
        __syncthreads();
    }
    int ex = tmp[tid] - t;
    if (base + 0 < n) excl[base + 0] = ex;
    if (base + 1 < n) excl[base + 1] = ex + v0;
    if (base + 2 < n) excl[base + 2] = ex + v0 + v1;
    if (base + 3 < n) excl[base + 3] = ex + v0 + v1 + v2;
    if (tid == 255) bsums[blockIdx.x] = tmp[255];
}

// single-block exclusive scan of block sums (nb <= 256)
__global__ void k_scan2(int* bsums, int nb) {
    __shared__ int tmp[256];
    int tid = threadIdx.x;
    int t = (tid < nb) ? bsums[tid] : 0;
    tmp[tid] = t;
    __syncthreads();
    for (int off = 1; off < 256; off <<= 1) {
        int u = (tid >= off) ? tmp[tid - off] : 0;
        __syncthreads();
        tmp[tid] += u;
        __syncthreads();
    }
    if (tid < nb) bsums[tid] = tmp[tid] - t;
}

__global__ void k_finalize(int* __restrict__ rowPtr, int* __restrict__ cursor,
                           const int* __restrict__ bsums, int n, int E) {
    int i = blockIdx.x * blockDim.x + threadIdx.x;
    if (i < n) {
        int v = rowPtr[i] + bsums[i >> 10];
        rowPtr[i] = v;
        cursor[i] = v;
    }
    if (i == 0) rowPtr[n] = E;
}

__global__ void k_fill(const int* __restrict__ srcA, const int* __restrict__ dstA,
                       const float* __restrict__ dinv, int* __restrict__ cursor,
                       int* __restrict__ eSrc, float* __restrict__ eW, int nE) {
    int e = blockIdx.x * blockDim.x + threadIdx.x;
    if (e < nE) {
        int s = srcA[e];
        int d = dstA[e];
        if ((unsigned)s < (unsigned)NNODES && (unsigned)d < (unsigned)NNODES) {
            int pos = atomicAdd(&cursor[d], 1);
            eSrc[pos] = s;
            eW[pos] = dinv[s];
        }
    }
}

// wave per node: gather agg row in registers, then MLP in-register -> sv[node]
__global__ __launch_bounds__(256) void k_agg_mlp(const float* __restrict__ X,
                                                 const int* __restrict__ rowPtr,
                                                 const int* __restrict__ eSrc,
                                                 const float* __restrict__ eW,
                                                 const float* __restrict__ dinv,
                                                 const float* __restrict__ W1,
                                                 const float* __restrict__ b1,
                                                 const float* __restrict__ W2,
                                                 float* __restrict__ sv, int n) {
    __shared__ float W1s[INF * HID];  // 32 KB
    __shared__ float b1s[HID];
    __shared__ float W2s[HID];
    for (int i = threadIdx.x; i < INF * HID / 4; i += blockDim.x)
        ((float4*)W1s)[i] = ((const float4*)W1)[i];
    if (threadIdx.x < HID) {
        b1s[threadIdx.x] = b1[threadIdx.x];
        W2s[threadIdx.x] = W2[threadIdx.x];
    }
    __syncthreads();

    int lane = threadIdx.x & 63;
    int node = (blockIdx.x * blockDim.x + threadIdx.x) >> 6;
    if (node >= n) return;

    int beg = rowPtr[node];
    int end = rowPtr[node + 1];
    float dD = dinv[node];
    // a = dD*x_node + sum_e w_e * x_src ; agg = dD * a
    float a = dD * X[(size_t)node * INF + lane];
    for (int j0 = beg; j0 < end; j0 += 64) {
        int m = min(64, end - j0);
        int ev = 0;
        float wv = 0.0f;
        if (lane < m) {
            ev = eSrc[j0 + lane];
            wv = eW[j0 + lane];
        }
        for (int j = 0; j < m; ++j) {
            int s = __shfl(ev, j, 64);
            float w = __shfl(wv, j, 64);
            a = fmaf(w, X[(size_t)s * INF + lane], a);
        }
    }
    a *= dD;  // lane holds aggX[node][lane]

    float a0 = 0.0f, a1 = 0.0f;
#pragma unroll
    for (int k = 0; k < INF; ++k) {
        float xk = __shfl(a, k, 64);
        a0 = fmaf(xk, W1s[k * HID + lane], a0);
        a1 = fmaf(xk, W1s[k * HID + 64 + lane], a1);
    }
    float h0 = fmaxf(a0 + b1s[lane], 0.0f);
    float h1 = fmaxf(a1 + b1s[64 + lane], 0.0f);
    float p = h0 * W2s[lane] + h1 * W2s[64 + lane];
#pragma unroll
    for (int off = 32; off > 0; off >>= 1) p += __shfl_xor(p, off, 64);
    if (lane == 0) sv[node] = p;
}

// wave per node: out[node] = dD*sum_e(w_e*sv[src]) + dD^2*sv[node] + b2
__global__ __launch_bounds__(256) void k_out(const int* __restrict__ rowPtr,
                                             const int* __restrict__ eSrc,
                                             const float* __restrict__ eW,
                                             const float* __restrict__ dinv,
                                             const float* __restrict__ sv,
                                             const float* __restrict__ b2,
                                             float* __restrict__ out, int n) {
    int lane = threadIdx.x & 63;
    int node = (blockIdx.x * blockDim.x + threadIdx.x) >> 6;
    if (node >= n) return;
    int beg = rowPtr[node];
    int end = rowPtr[node + 1];
    float p = 0.0f;
    for (int j = beg + lane; j < end; j += 64) p += eW[j] * sv[eSrc[j]];
#pragma unroll
    for (int off = 32; off > 0; off >>= 1) p += __shfl_xor(p, off, 64);
    if (lane == 0) {
        float dD = dinv[node];
        out[node] = dD * p + dD * dD * sv[node] + b2[0];
    }
}

extern "C" void kernel_launch(void* const* d_in, const int* in_sizes, int n_in,
                              void* d_out, int out_size, void* d_ws, size_t ws_size,
                              hipStream_t stream) {
    const float* X  = (const float*)d_in[0];
    const int*   ei = (const int*)d_in[1];   // int32 (jax x64 disabled)
    const float* W1 = (const float*)d_in[2];
    const float* b1 = (const float*)d_in[3];
    const float* W2 = (const float*)d_in[4];
    const float* b2 = (const float*)d_in[5];

    int N = in_sizes[0] / INF;  // 100000
    int E = in_sizes[1] / 2;    // 1600000
    const int* srcA = ei;
    const int* dstA = ei + E;

    // workspace layout (all 4B types)
    int*   counts = (int*)d_ws;          // N
    int*   rowPtr = counts + N;          // N+1
    int*   cursor = rowPtr + N + 1;      // N
    int*   bsums  = cursor + N;          // 256
    int*   eSrc   = bsums + 256;         // E
    float* eW     = (float*)(eSrc + E);  // E
    float* dinv   = eW + E;              // N
    float* sv     = dinv + N;            // N
    float* out    = (float*)d_out;

    int nbN  = (N + 255) / 256;
    int nbE  = (E + 255) / 256;
    int nb1  = (N + 1023) / 1024;                 // 98 blocks for scan1
    int nbWN = ((N * 64) + 255) / 256;            // wave-per-node grids

    k_zero<<<nbN, 256, 0, stream>>>(counts, N);
    k_hist<<<nbE, 256, 0, stream>>>(dstA, counts, E);
    k_dinv<<<nbN, 256, 0, stream>>>(counts, dinv, N);
    k_scan1<<<nb1, 256, 0, stream>>>(counts, rowPtr, bsums, N);
    k_scan2<<<1, 256, 0, stream>>>(bsums, nb1);
    k_finalize<<<nbN, 256, 0, stream>>>(rowPtr, cursor, bsums, N, E);
    k_fill<<<nbE, 256, 0, stream>>>(srcA, dstA, dinv, cursor, eSrc, eW, E);
    k_agg_mlp<<<nbWN, 256, 0, stream>>>(X, rowPtr, eSrc, eW, dinv, W1, b1, W2, sv, N);
    k_out<<<nbWN, 256, 0, stream>>>(rowPtr, eSrc, eW, dinv, sv, b2, out, N);
}

// Round 3
// 343.121 us; speedup vs baseline: 1.7665x; 1.4877x over previous
//
#include <hip/hip_runtime.h>

// GCN 2-layer forward, f32 — CSR-gather, quarter-wave float4 edge gather.
// Algebra: A_hat(X@W1) = (A_hat X)@W1; layer 2 is scalar aggregation of s=h@W2.

#define NNODES 100000
#define INF 64
#define HID 128

typedef unsigned long long u64;

__global__ void k_hist(const int* __restrict__ dst, int* __restrict__ cnt, int nE) {
    int e = blockIdx.x * blockDim.x + threadIdx.x;
    if (e < nE) {
        int d = dst[e];
        if ((unsigned)d < (unsigned)NNODES) atomicAdd(&cnt[d], 1);
    }
}

// block-level exclusive scan: 256 thr x 4 elems = 1024/block
__global__ void k_scan1(const int* __restrict__ cnt, int* __restrict__ excl,
                        int* __restrict__ bsums, int n) {
    __shared__ int tmp[256];
    int tid = threadIdx.x;
    int base = blockIdx.x * 1024 + tid * 4;
    int v0 = (base + 0 < n) ? cnt[base + 0] : 0;
    int v1 = (base + 1 < n) ? cnt[base + 1] : 0;
    int v2 = (base + 2 < n) ? cnt[base + 2] : 0;
    int v3 = (base + 3 < n) ? cnt[base + 3] : 0;
    int t = v0 + v1 + v2 + v3;
    tmp[tid] = t;
    __syncthreads();
    for (int off = 1; off < 256; off <<= 1) {
        int u = (tid >= off) ? tmp[tid - off] : 0;
        __syncthreads();
        tmp[tid] += u;
        __syncthreads();
    }
    int ex = tmp[tid] - t;
    if (base + 0 < n) excl[base + 0] = ex;
    if (base + 1 < n) excl[base + 1] = ex + v0;
    if (base + 2 < n) excl[base + 2] = ex + v0 + v1;
    if (base + 3 < n) excl[base + 3] = ex + v0 + v1 + v2;
    if (tid == 255) bsums[blockIdx.x] = tmp[255];
}

__global__ void k_scan2(int* bsums, int nb) {
    __shared__ int tmp[256];
    int tid = threadIdx.x;
    int t = (tid < nb) ? bsums[tid] : 0;
    tmp[tid] = t;
    __syncthreads();
    for (int off = 1; off < 256; off <<= 1) {
        int u = (tid >= off) ? tmp[tid - off] : 0;
        __syncthreads();
        tmp[tid] += u;
        __syncthreads();
    }
    if (tid < nb) bsums[tid] = tmp[tid] - t;
}

// finalize rowPtr/cursor + compute dinv (folded)
__global__ void k_finalize(int* __restrict__ rowPtr, int* __restrict__ cursor,
                           const int* __restrict__ bsums, const int* __restrict__ counts,
                           float* __restrict__ dinv, int n, int E) {
    int i = blockIdx.x * blockDim.x + threadIdx.x;
    if (i < n) {
        int v = rowPtr[i] + bsums[i >> 10];
        rowPtr[i] = v;
        cursor[i] = v;
        dinv[i] = rsqrtf((float)(counts[i] + 1));  // +1 self loop
    }
    if (i == 0) rowPtr[n] = E;
}

// fill CSR with packed (src, w=dinv[src]) 8B records
__global__ void k_fill(const int* __restrict__ srcA, const int* __restrict__ dstA,
                       const float* __restrict__ dinv, int* __restrict__ cursor,
                       u64* __restrict__ eSW, int nE) {
    int e = blockIdx.x * blockDim.x + threadIdx.x;
    if (e < nE) {
        int s = srcA[e];
        int d = dstA[e];
        if ((unsigned)s < (unsigned)NNODES && (unsigned)d < (unsigned)NNODES) {
            int pos = atomicAdd(&cursor[d], 1);
            eSW[pos] = (u64)(unsigned)s | ((u64)__float_as_uint(dinv[s]) << 32);
        }
    }
}

// wave per node, quarter-wave (16 lanes x float4) per edge, 2x unroll.
// Then in-register MLP: sv[node] = dot(relu(agg@W1 + b1), W2)
__global__ __launch_bounds__(1024) void k_agg_mlp(const float4* __restrict__ X4,
                                                  const int* __restrict__ rowPtr,
                                                  const u64* __restrict__ eSW,
                                                  const float* __restrict__ dinv,
                                                  const float* __restrict__ W1,
                                                  const float* __restrict__ b1,
                                                  const float* __restrict__ W2,
                                                  float* __restrict__ sv, int n) {
    __shared__ float W1s[INF * HID];  // 32 KB
    __shared__ float b1s[HID];
    __shared__ float W2s[HID];
    for (int i = threadIdx.x; i < INF * HID / 4; i += blockDim.x)
        ((float4*)W1s)[i] = ((const float4*)W1)[i];
    if (threadIdx.x < HID) {
        b1s[threadIdx.x] = b1[threadIdx.x];
        W2s[threadIdx.x] = W2[threadIdx.x];
    }
    __syncthreads();

    int lane = threadIdx.x & 63;
    int r = lane & 15;        // float4 slot within row
    int q = lane >> 4;        // quarter = which edge of a group of 4
    int node = (blockIdx.x * blockDim.x + threadIdx.x) >> 6;
    if (node >= n) return;

    int beg = rowPtr[node];
    int end = rowPtr[node + 1];
    float dD = dinv[node];

    // self-loop term (only quarter 0 contributes)
    float4 xn = X4[(size_t)node * 16 + r];
    float c = (q == 0) ? dD : 0.0f;
    float4 acc;
    acc.x = c * xn.x; acc.y = c * xn.y; acc.z = c * xn.z; acc.w = c * xn.w;

    int j = beg + q;
    for (; j + 4 < end; j += 8) {
        u64 p0 = eSW[j];
        u64 p1 = eSW[j + 4];
        int s0 = (int)(unsigned)p0; float w0 = __uint_as_float((unsigned)(p0 >> 32));
        int s1 = (int)(unsigned)p1; float w1 = __uint_as_float((unsigned)(p1 >> 32));
        float4 x0 = X4[(size_t)s0 * 16 + r];
        float4 x1 = X4[(size_t)s1 * 16 + r];
        acc.x = fmaf(w0, x0.x, acc.x); acc.y = fmaf(w0, x0.y, acc.y);
        acc.z = fmaf(w0, x0.z, acc.z); acc.w = fmaf(w0, x0.w, acc.w);
        acc.x = fmaf(w1, x1.x, acc.x); acc.y = fmaf(w1, x1.y, acc.y);
        acc.z = fmaf(w1, x1.z, acc.z); acc.w = fmaf(w1, x1.w, acc.w);
    }
    if (j < end) {
        u64 p0 = eSW[j];
        int s0 = (int)(unsigned)p0; float w0 = __uint_as_float((unsigned)(p0 >> 32));
        float4 x0 = X4[(size_t)s0 * 16 + r];
        acc.x = fmaf(w0, x0.x, acc.x); acc.y = fmaf(w0, x0.y, acc.y);
        acc.z = fmaf(w0, x0.z, acc.z); acc.w = fmaf(w0, x0.w, acc.w);
    }

    // reduce the 4 quarters; afterwards every lane with same r holds full sum
    acc.x += __shfl_xor(acc.x, 16, 64); acc.y += __shfl_xor(acc.y, 16, 64);
    acc.z += __shfl_xor(acc.z, 16, 64); acc.w += __shfl_xor(acc.w, 16, 64);
    acc.x += __shfl_xor(acc.x, 32, 64); acc.y += __shfl_xor(acc.y, 32, 64);
    acc.z += __shfl_xor(acc.z, 32, 64); acc.w += __shfl_xor(acc.w, 32, 64);

    // agg[4r+c] = dD * acc.c   (lane r, any quarter)
    float av0 = dD * acc.x, av1 = dD * acc.y, av2 = dD * acc.z, av3 = dD * acc.w;

    float a0 = 0.0f, a1 = 0.0f;
#pragma unroll
    for (int k = 0; k < INF; ++k) {
        float srcv = ((k & 3) == 0) ? av0 : ((k & 3) == 1) ? av1 : ((k & 3) == 2) ? av2 : av3;
        float xk = __shfl(srcv, k >> 2, 64);  // feature k lives in lane k>>2, comp k&3
        a0 = fmaf(xk, W1s[k * HID + lane], a0);
        a1 = fmaf(xk, W1s[k * HID + 64 + lane], a1);
    }
    float h0 = fmaxf(a0 + b1s[lane], 0.0f);
    float h1 = fmaxf(a1 + b1s[64 + lane], 0.0f);
    float p = h0 * W2s[lane] + h1 * W2s[64 + lane];
#pragma unroll
    for (int off = 32; off > 0; off >>= 1) p += __shfl_xor(p, off, 64);
    if (lane == 0) sv[node] = p;
}

// 4 nodes per wave (16-lane segments): out = dD*sum(w*sv[src]) + dD^2*sv[node] + b2
__global__ __launch_bounds__(256) void k_out(const int* __restrict__ rowPtr,
                                             const u64* __restrict__ eSW,
                                             const float* __restrict__ dinv,
                                             const float* __restrict__ sv,
                                             const float* __restrict__ b2,
                                             float* __restrict__ out, int n) {
    int t = blockIdx.x * blockDim.x + threadIdx.x;
    int node = t >> 4;
    int r = t & 15;
    if (node >= n) return;
    int beg = rowPtr[node];
    int end = rowPtr[node + 1];
    float p = 0.0f;
    for (int j = beg + r; j < end; j += 16) {
        u64 pe = eSW[j];
        int s = (int)(unsigned)pe;
        float w = __uint_as_float((unsigned)(pe >> 32));
        p = fmaf(w, sv[s], p);
    }
    p += __shfl_xor(p, 1, 16);
    p += __shfl_xor(p, 2, 16);
    p += __shfl_xor(p, 4, 16);
    p += __shfl_xor(p, 8, 16);
    if (r == 0) {
        float dD = dinv[node];
        out[node] = fmaf(dD, p, fmaf(dD * dD, sv[node], b2[0]));
    }
}

extern "C" void kernel_launch(void* const* d_in, const int* in_sizes, int n_in,
                              void* d_out, int out_size, void* d_ws, size_t ws_size,
                              hipStream_t stream) {
    const float* X  = (const float*)d_in[0];
    const int*   ei = (const int*)d_in[1];   // int32 (jax x64 disabled)
    const float* W1 = (const float*)d_in[2];
    const float* b1 = (const float*)d_in[3];
    const float* W2 = (const float*)d_in[4];
    const float* b2 = (const float*)d_in[5];

    int N = in_sizes[0] / INF;  // 100000
    int E = in_sizes[1] / 2;    // 1600000

    const int* srcA = ei;
    const int* dstA = ei + E;

    // workspace layout (eSW first for 8B alignment)
    u64*   eSW    = (u64*)d_ws;             // E
    int*   counts = (int*)(eSW + E);        // N
    int*   rowPtr = counts + N;             // N+1
    int*   cursor = rowPtr + N + 1;         // N
    int*   bsums  = cursor + N;             // 256
    float* dinv   = (float*)(bsums + 256);  // N
    float* sv     = dinv + N;               // N
    float* out    = (float*)d_out;

    int nbN = (N + 255) / 256;
    int nbE = (E + 255) / 256;
    int nb1 = (N + 1023) / 1024;  // 98 blocks for scan1

    hipMemsetAsync(counts, 0, (size_t)N * sizeof(int), stream);
    k_hist<<<nbE, 256, 0, stream>>>(dstA, counts, E);
    k_scan1<<<nb1, 256, 0, stream>>>(counts, rowPtr, bsums, N);
    k_scan2<<<1, 256, 0, stream>>>(bsums, nb1);
    k_finalize<<<nbN, 256, 0, stream>>>(rowPtr, cursor, bsums, counts, dinv, N, E);
    k_fill<<<nbE, 256, 0, stream>>>(srcA, dstA, dinv, cursor, eSW, E);
    k_agg_mlp<<<(N * 64 + 1023) / 1024, 1024, 0, stream>>>((const float4*)X, rowPtr, eSW,
                                                           dinv, W1, b1, W2, sv, N);
    k_out<<<(N * 16 + 255) / 256, 256, 0, stream>>>(rowPtr, eSW, dinv, sv, b2, out, N);
}